// Round 8
// baseline (8850.529 us; speedup 1.0000x reference)
//
#include <hip/hip_runtime.h>
#include <cstddef>
#include <cstdint>

typedef unsigned long long ull;
typedef unsigned short u16;
typedef unsigned int u32;
typedef __attribute__((ext_vector_type(8))) short s8v;   // 8 x bf16 (MFMA A/B frag)
typedef __attribute__((ext_vector_type(4))) float f4v;   // MFMA C/D frag
typedef __attribute__((ext_vector_type(4))) u32 u32x4;   // dwordx4 payload

#define GROUPS 8
#define BG     16
#define JS     16
#define TPB    256
#define NT     1024
#define HDIM   512
#define INDIM  17
#define OUTDIM 17
#define BTOT   128

// Cross-WG traffic: tag-in-data planes. AUTHORITATIVE path = relaxed agent
// atomics / sc1 vector ops (MALL). FAST path = sc0 (XCD-shared L2): producers
// dual-store sc0+sc1, consumers try sc0 first (valid when the group's 32 WGs
// share an XCD under round-robin dispatch; R2's sc0 failed because stores were
// sc1-only -> L2 provably stale). Tag-verify + sc1 fallback keeps correctness
// under ANY WG->XCD mapping. NO release fences in the hot loop (R6: agent
// release emits buffer_wbl2 = catastrophic).
#define AT_LD(p)   __hip_atomic_load((p), __ATOMIC_RELAXED, __HIP_MEMORY_SCOPE_AGENT)
#define AT_ST(p,v) __hip_atomic_store((p), (v), __ATOMIC_RELAXED, __HIP_MEMORY_SCOPE_AGENT)

// frag-order plane, u32 elements: entry = (step_tag << 16) | bf16_h.
// u32 idx(k,b) = (k>>5)*512 + ((k>>3)&3)*128 + b*8 + (k&7); plane = 8192 u32 = 32KB.
#define PLANE32 8192
#define WIDX(k, b) ((((k) >> 5) * 512) + ((((k) >> 3) & 3) * 128) + ((b) * 8) + ((k) & 7))

// ---------------- workspace ----------------
#define RA_OFF     ((size_t)0)
#define RING_BYTES ((size_t)4 * GROUPS * PLANE32 * 4)   // 4-slot ring, 1 MB
#define RB_OFF     (RA_OFF + RING_BYTES)
#define FB32_OFF   (RB_OFF + RING_BYTES)                // fp32 h1[NT]: 256 KB
#define WS_NEEDED  (FB32_OFF + (size_t)BTOT * HDIM * 4)
#define RIX32(sl, gr) (((size_t)(sl) * GROUPS + (gr)) * PLANE32)

// ---------------- LDS layout ----------------
#define L_H0   0                        // h0 stage ring: 3 slots x 16 KB (bf16 frag-order)
#define L_H1   49152                    // h1 stage: 16 KB
#define L_STG  65536                    // per-wave publish transpose: 4 x 512 B
#define L_CTL  67584                    // control ints (64 B)
#define LDS_SZ 82944                    // >80KB: 2 WGs cannot share a CU
// ctl: 0=ctrA 1=ctrB 4..6=stage_ready[3] 7,8=L1 per-wave progress (back-pressure)

__device__ __forceinline__ u16 f2bf(float f) {
  unsigned int u = __float_as_uint(f);
  u += 0x7FFFu + ((u >> 16) & 1u);
  return (u16)(u >> 16);
}
__device__ __forceinline__ float bf2f(u16 h) {
  return __uint_as_float(((unsigned int)h) << 16);
}
__device__ __forceinline__ float sigm(float x) { return 1.f / (1.f + __expf(-x)); }
__device__ __forceinline__ float tanh_f(float x) { return 2.f / (1.f + __expf(-2.f * x)) - 1.f; }

#define MFMA(a, b, c) __builtin_amdgcn_mfma_f32_16x16x32_bf16((a), (b), (c), 0, 0, 0)

// sc0 8B load (L1-bypass, served by the XCD-shared L2): fast freshness probe.
__device__ __forceinline__ ull sc0_read8(const ull* p) {
  ull w;
  asm volatile("global_load_dwordx2 %0, %1, off sc0\n\ts_waitcnt vmcnt(0)"
               : "=&v"(w) : "v"(p) : "memory");
  return w;
}

// 16 x dwordx4 loads: one half-plane (16KB) per wave, 64 u32/lane.
// Tag-verified by caller. sc0 = XCD-L2 fast path; sc1 = MALL authoritative.
#define READ16_BODY(FLAG)                                                  \
  asm volatile(                                                            \
      "global_load_dwordx4 %0, %16, off " FLAG "\n\t"                      \
      "global_load_dwordx4 %1, %16, off offset:1024 " FLAG "\n\t"          \
      "global_load_dwordx4 %2, %16, off offset:2048 " FLAG "\n\t"          \
      "global_load_dwordx4 %3, %16, off offset:3072 " FLAG "\n\t"          \
      "global_load_dwordx4 %4, %17, off " FLAG "\n\t"                      \
      "global_load_dwordx4 %5, %17, off offset:1024 " FLAG "\n\t"          \
      "global_load_dwordx4 %6, %17, off offset:2048 " FLAG "\n\t"          \
      "global_load_dwordx4 %7, %17, off offset:3072 " FLAG "\n\t"          \
      "global_load_dwordx4 %8, %18, off " FLAG "\n\t"                      \
      "global_load_dwordx4 %9, %18, off offset:1024 " FLAG "\n\t"          \
      "global_load_dwordx4 %10, %18, off offset:2048 " FLAG "\n\t"         \
      "global_load_dwordx4 %11, %18, off offset:3072 " FLAG "\n\t"         \
      "global_load_dwordx4 %12, %19, off " FLAG "\n\t"                     \
      "global_load_dwordx4 %13, %19, off offset:1024 " FLAG "\n\t"         \
      "global_load_dwordx4 %14, %19, off offset:2048 " FLAG "\n\t"         \
      "global_load_dwordx4 %15, %19, off offset:3072 " FLAG "\n\t"         \
      "s_waitcnt vmcnt(0)"                                                 \
      : "=&v"(r[0]), "=&v"(r[1]), "=&v"(r[2]), "=&v"(r[3]),                \
        "=&v"(r[4]), "=&v"(r[5]), "=&v"(r[6]), "=&v"(r[7]),                \
        "=&v"(r[8]), "=&v"(r[9]), "=&v"(r[10]), "=&v"(r[11]),              \
        "=&v"(r[12]), "=&v"(r[13]), "=&v"(r[14]), "=&v"(r[15])             \
      : "v"(base), "v"(base + 4096), "v"(base + 8192), "v"(base + 12288)   \
      : "memory")

__device__ __forceinline__ void sc1_read16(const char* base, u32x4 r[16]) {
  READ16_BODY("sc1");
}
__device__ __forceinline__ void sc0_read16(const char* base, u32x4 r[16]) {
  READ16_BODY("sc0");
}

// 2-wave pair barrier via LDS monotonic counter (lane0 adds, all spin)
__device__ __forceinline__ void pbar(int* c, int& nbar, int lane) {
  ++nbar;
  if (lane == 0)
    (void)__hip_atomic_fetch_add(c, 1, __ATOMIC_RELEASE, __HIP_MEMORY_SCOPE_WORKGROUP);
  while (__hip_atomic_load(c, __ATOMIC_ACQUIRE, __HIP_MEMORY_SCOPE_WORKGROUP) < 2 * nbar) {}
}

// ---------------- fused 2-layer persistent LSTM, tag-in-data sync ---------------
// 256 WGs (1/CU). gr = bid&7 owns batches [gr*16,..); wg = bid>>3 owns j-slice.
// Waves 0-1 = L0; waves 2-3 = L1. OPERAND-SWAPPED MFMA: C = W(A) x h(B), A rows
// packed (j_local*4+gate) -> all 4 gates thread-local, no gate exchange.
// h comm = (tag<<16|bf16) u32. PUBLISH: per-wave LDS transpose -> 32 lanes dual
// dwordx4 stores sc0 (XCD L2) + sc1 (MALL mirror). CONSUME: two-stage poll;
// stage1 subset spin (sc0, every-8th sc1 for progress), stage2 wide read:
// 2 sc0 attempts -> sc1 verify-spin; 4 consecutive sc0 misses -> fast=0.
// Slot safety: WG at step s observed all peers' s-1 tags => all peers >= s-1 =>
// nobody still reads slot (s&3)'s old s-4 contents. Harness re-poisons ws
// (0xAAAA tag) so stale tags never match. Cell state fp32 in regs; h1 fp32 out.
__global__ __launch_bounds__(TPB, 1) void lstm_fused(
    const float* __restrict__ x,
    const float* __restrict__ wih0, const float* __restrict__ whh0,
    const float* __restrict__ bih0, const float* __restrict__ bhh0,
    const float* __restrict__ wih1, const float* __restrict__ whh1,
    const float* __restrict__ bih1, const float* __restrict__ bhh1,
    u32* __restrict__ ringA, u32* __restrict__ ringB,
    float* __restrict__ fb32)
{
  const int bid  = blockIdx.x;
  const int gr   = bid & 7;
  const int wg   = bid >> 3;
  const int j0   = wg * JS;
  const int tid  = threadIdx.x;
  const int wave = tid >> 6;
  const int lane = tid & 63;
  const int n    = lane & 15;        // own-index: B col (batch) / A row (j,g packed)
  const int q    = lane >> 4;        // k-sub-quad; also C-row quad -> own j_local
  const int k0   = q * 8;
  const int gidx = n & 3;            // gate for WEIGHT A-frag row
  const int jl   = n >> 2;           // j_local for WEIGHT A-frag row

  __shared__ __align__(16) char smem[LDS_SZ];
  int* ctl = (int*)(smem + L_CTL);
  u32* stg = (u32*)(smem + L_STG + (wave & 1) * 512 + (wave >> 1) * 1024);

  if (tid < 16) ctl[tid] = 0;

  // ---- init ring slot 0 = (tag=0, h=0) for own slice: dual-store sc0+sc1 so
  // prior-launch L2 residue cannot fake-out the fast path ----
  {
    int b_l = tid >> 4, j_l = tid & 15, jgw = j0 + j_l;
    int wo = WIDX(jgw, b_l);
    u32* pa = &ringA[RIX32(0, gr) + wo];
    u32* pb = &ringB[RIX32(0, gr) + wo];
    u32 zz = 0u;
    asm volatile("global_store_dword %0, %2, off sc0\n\t"
                 "global_store_dword %1, %2, off sc0"
                 :: "v"(pa), "v"(pb), "v"(zz) : "memory");
    AT_ST(pa, 0u);
    AT_ST(pb, 0u);
  }
  __syncthreads();  // ctl visible; only __syncthreads in kernel

  const f4v z = {0.f, 0.f, 0.f, 0.f};
  const int half = wave & 1;              // which half-plane this wave polls+stages
  // wave's contiguous 64-ull publish block within the plane (ull units):
  const int pub = (wg >> 1) * 256 + ((wg & 1) * 2 + (wave & 1)) * 64;
  // subset sample: lane covers peer slice (lane>>2) of this half, ull (lane&3)*32
  const int sub = (lane >> 2) * 128 + (lane & 3) * 32;   // ull index in half-plane
  const ull TMASK = 0xFFFF0000FFFF0000ULL;

  if (wave < 2) {
    // ================= L0 pipeline (waves 0,1) =================
    // chains ii=0,1 -> jc = wave*2+ii; this thread owns cells (b=n, j=j0+jc*4+q)
    int jown[2];
    float bias[2][4];
    s8v wxh[2], wxl[2];                 // wih0 A-frags (hi/lo), K=32 (17 padded)
    s8v whh_[2][16], whl_[2][16];       // whh0 A-frags (hi/lo)
#pragma unroll
    for (int i = 0; i < 2; ++i) {
      const int jc = wave * 2 + i;
      jown[i] = j0 + jc * 4 + q;
      const float* wr = wih0 + (size_t)(gidx * HDIM + j0 + jc * 4 + jl) * INDIM;
#pragma unroll
      for (int j = 0; j < 8; ++j) {
        int k = k0 + j;
        float v = (k < INDIM) ? wr[k] : 0.f;
        u16 hi = f2bf(v);
        wxh[i][j] = (short)hi;
        wxl[i][j] = (short)f2bf(v - bf2f(hi));
      }
      const float* hr = whh0 + (size_t)(gidx * HDIM + j0 + jc * 4 + jl) * HDIM;
#pragma unroll
      for (int kt = 0; kt < 16; ++kt)
#pragma unroll
        for (int j = 0; j < 8; ++j) {
          float v = hr[kt * 32 + k0 + j];
          u16 hi = f2bf(v);
          whh_[i][kt][j] = (short)hi;
          whl_[i][kt][j] = (short)f2bf(v - bf2f(hi));
        }
#pragma unroll
      for (int g = 0; g < 4; ++g)
        bias[i][g] = bih0[g * HDIM + jown[i]] + bhh0[g * HDIM + jown[i]];
    }
    float cc[2] = {0.f, 0.f};
    int nbar = 0, fast = 1, miss = 0;

    for (int s = 1; s <= NT + 1; ++s) {
      // x-part (no peer dependency): before the data-poll. B-frag = x (col=batch n)
      f4v xa[2] = {z, z};
      if (s <= NT) {
        const float* xr = x + ((size_t)(gr * BG + n) * NT + (s - 1)) * INDIM;
        s8v bxh, bxl;
#pragma unroll
        for (int j = 0; j < 8; ++j) {
          int k = k0 + j;
          float v = (k < INDIM) ? xr[k] : 0.f;
          u16 hi = f2bf(v);
          bxh[j] = (short)hi;
          bxl[j] = (short)f2bf(v - bf2f(hi));
        }
#pragma unroll
        for (int i = 0; i < 2; ++i) {
          xa[i] = MFMA(wxh[i], bxh, xa[i]);
          xa[i] = MFMA(wxh[i], bxl, xa[i]);
          xa[i] = MFMA(wxl[i], bxh, xa[i]);
        }
      }
      // two-stage tag-poll + stage own half of h0[s-1] (slot (s-1)&3, tag s-1);
      // back-pressure: BOTH L1 waves must have consumed h0[s-4] before LDS reuse
      const int sl3 = (s - 1) % 3;
      {
        const char* srcb = (const char*)(ringA + RIX32((s - 1) & 3, gr))
                         + half * 16384;
        const ull tg = (ull)(u16)(s - 1);
        const ull pat = (tg << 16) | (tg << 48);
        const u32 t32 = ((u32)(u16)(s - 1)) << 16;
        // stage 1: subset spin (sc0 fast, every-8th iter sc1 authoritative)
        int it = 0;
        for (;;) {
          ull w;
          if (fast && (((++it) & 7) != 0)) w = sc0_read8((const ull*)srcb + sub);
          else                             w = AT_LD((const ull*)srcb + sub);
          int l1a = __hip_atomic_load(&ctl[7], __ATOMIC_ACQUIRE,
                                      __HIP_MEMORY_SCOPE_WORKGROUP);
          int l1b = __hip_atomic_load(&ctl[8], __ATOMIC_ACQUIRE,
                                      __HIP_MEMORY_SCOPE_WORKGROUP);
          int l1t = l1a < l1b ? l1a : l1b;
          if (__ballot((((w ^ pat) & TMASK) == 0) & (l1t >= s - 4)) == ~0ULL) break;
          if (!fast) __builtin_amdgcn_s_sleep(1);
        }
        // stage 2: wide full read + per-u32 tag verify (sc0 x2 -> sc1 spin)
        u32x4 r[16];
        const char* base = srcb + lane * 16;
        bool got = false;
        if (fast) {
#pragma unroll 1
          for (int att = 0; att < 2 && !got; ++att) {
            sc0_read16(base, r);
            u32 acc = 0;
#pragma unroll
            for (int i = 0; i < 16; ++i)
#pragma unroll
              for (int jj = 0; jj < 4; ++jj)
                acc |= (r[i][jj] ^ t32) & 0xFFFF0000u;
            got = (__ballot(acc == 0) == ~0ULL);
          }
          miss = got ? 0 : miss + 1;
          if (miss >= 4) fast = 0;   // mapping wrong -> sc1-only from here on
        }
        if (!got) {
          for (;;) {
            sc1_read16(base, r);
            u32 acc = 0;
#pragma unroll
            for (int i = 0; i < 16; ++i)
#pragma unroll
              for (int jj = 0; jj < 4; ++jj)
                acc |= (r[i][jj] ^ t32) & 0xFFFF0000u;
            if (__ballot(acc == 0) == ~0ULL) break;
            __builtin_amdgcn_s_sleep(1);
          }
        }
        char* dst = smem + L_H0 + sl3 * 16384 + half * 8192;
#pragma unroll
        for (int i = 0; i < 16; ++i) {
          ull packed = (ull)((r[i][0] & 0xFFFFu) | (r[i][1] << 16))
                     | ((ull)((r[i][2] & 0xFFFFu) | (r[i][3] << 16)) << 32);
          *(ull*)(dst + (i * 64 + lane) * 8) = packed;
        }
      }
      pbar(&ctl[0], nbar, lane);                              // P1: stage visible
      if (wave == 0 && lane == 0)
        __hip_atomic_store(&ctl[4 + sl3], s - 1, __ATOMIC_RELEASE,
                           __HIP_MEMORY_SCOPE_WORKGROUP);
      if (s == NT + 1) break;  // tail step only feeds L1's last x-input

      // K-loop: 16 ds_read_b128 + 64 MFMA; A=Whh frags, B=h frags from LDS
      const char* sh = smem + L_H0 + sl3 * 16384;
      f4v cHH[2] = {z, z}, cHL[2] = {z, z};
#pragma unroll
      for (int kt = 0; kt < 16; ++kt) {
        s8v bh = *(const s8v*)(sh + kt * 1024 + q * 256 + n * 16);
#pragma unroll
        for (int i = 0; i < 2; ++i) {
          cHH[i] = MFMA(whh_[i][kt], bh, cHH[i]);
          cHL[i] = MFMA(whl_[i][kt], bh, cHL[i]);
        }
      }
      // elementwise: all 4 gates thread-local (C rows q*4+r). Publish via
      // intra-wave LDS transpose -> 32 lanes dual dwordx4 (sc0 + sc1 mirror).
      const u32 otag = ((u32)(u16)s) << 16;
#pragma unroll
      for (int ii = 0; ii < 2; ++ii) {
        f4v e = xa[ii] + cHH[ii] + cHL[ii];
        float pi = e[0] + bias[ii][0], pf = e[1] + bias[ii][1];
        float pg = e[2] + bias[ii][2], po = e[3] + bias[ii][3];
        float ig = sigm(pi), fg = sigm(pf), gv = tanh_f(pg), og = sigm(po);
        cc[ii] = fg * cc[ii] + ig * gv;
        stg[n * 8 + ii * 4 + q] = otag | (u32)f2bf(og * tanh_f(cc[ii]));
      }
      asm volatile("s_waitcnt lgkmcnt(0)" ::: "memory");
      __builtin_amdgcn_sched_barrier(0);
      if (lane < 32) {
        u32x4 pv = *(const u32x4*)((const char*)stg + lane * 16);
        u32* dp = ringA + RIX32(s & 3, gr) + pub * 2 + lane * 4;
        asm volatile("global_store_dwordx4 %0, %1, off sc0\n\t"
                     "global_store_dwordx4 %0, %1, off sc1"
                     :: "v"(dp), "v"(pv) : "memory");
      }
    }
  } else {
    // ================= L1 pipeline (waves 2,3) =================
    int jown[2];
    float bias[2][4];
    s8v w1x_[2][16], w1h_[2][16];   // wih1 / whh1 A-frags (hi only)
#pragma unroll
    for (int i = 0; i < 2; ++i) {
      const int jc = (wave - 2) * 2 + i;
      jown[i] = j0 + jc * 4 + q;
      const float* p1 = wih1 + (size_t)(gidx * HDIM + j0 + jc * 4 + jl) * HDIM;
      const float* p2 = whh1 + (size_t)(gidx * HDIM + j0 + jc * 4 + jl) * HDIM;
#pragma unroll
      for (int kt = 0; kt < 16; ++kt)
#pragma unroll
        for (int j = 0; j < 8; ++j) {
          w1x_[i][kt][j] = (short)f2bf(p1[kt * 32 + k0 + j]);
          w1h_[i][kt][j] = (short)f2bf(p2[kt * 32 + k0 + j]);
        }
#pragma unroll
      for (int g = 0; g < 4; ++g)
        bias[i][g] = bih1[g * HDIM + jown[i]] + bhh1[g * HDIM + jown[i]];
    }
    float c1[2] = {0.f, 0.f};
    int nbar = 0, fast = 1, miss = 0;

    for (int t = 1; t <= NT; ++t) {
      // two-stage tag-poll + stage own half of h1[t-1] (slot (t-1)&3, tag t-1)
      {
        const char* srcb = (const char*)(ringB + RIX32((t - 1) & 3, gr))
                         + half * 16384;
        const ull tg = (ull)(u16)(t - 1);
        const ull pat = (tg << 16) | (tg << 48);
        const u32 t32 = ((u32)(u16)(t - 1)) << 16;
        int it = 0;
        for (;;) {
          ull w;
          if (fast && (((++it) & 7) != 0)) w = sc0_read8((const ull*)srcb + sub);
          else                             w = AT_LD((const ull*)srcb + sub);
          if (__ballot(((w ^ pat) & TMASK) == 0) == ~0ULL) break;
          if (!fast) __builtin_amdgcn_s_sleep(1);
        }
        u32x4 r[16];
        const char* base = srcb + lane * 16;
        bool got = false;
        if (fast) {
#pragma unroll 1
          for (int att = 0; att < 2 && !got; ++att) {
            sc0_read16(base, r);
            u32 acc = 0;
#pragma unroll
            for (int i = 0; i < 16; ++i)
#pragma unroll
              for (int jj = 0; jj < 4; ++jj)
                acc |= (r[i][jj] ^ t32) & 0xFFFF0000u;
            got = (__ballot(acc == 0) == ~0ULL);
          }
          miss = got ? 0 : miss + 1;
          if (miss >= 4) fast = 0;
        }
        if (!got) {
          for (;;) {
            sc1_read16(base, r);
            u32 acc = 0;
#pragma unroll
            for (int i = 0; i < 16; ++i)
#pragma unroll
              for (int jj = 0; jj < 4; ++jj)
                acc |= (r[i][jj] ^ t32) & 0xFFFF0000u;
            if (__ballot(acc == 0) == ~0ULL) break;
            __builtin_amdgcn_s_sleep(1);
          }
        }
        char* dst = smem + L_H1 + half * 8192;
#pragma unroll
        for (int i = 0; i < 16; ++i) {
          ull packed = (ull)((r[i][0] & 0xFFFFu) | (r[i][1] << 16))
                     | ((ull)((r[i][2] & 0xFFFFu) | (r[i][3] << 16)) << 32);
          *(ull*)(dst + (i * 64 + lane) * 8) = packed;
        }
      }
      pbar(&ctl[1], nbar, lane);                              // Q1: h1 staged
      // K-loop B: h1 recurrence (A=whh1 frags)
      const char* th = smem + L_H1;
      f4v dHH[2] = {z, z};
#pragma unroll
      for (int kt = 0; kt < 16; ++kt) {
        s8v bh = *(const s8v*)(th + kt * 1024 + q * 256 + n * 16);
#pragma unroll
        for (int i = 0; i < 2; ++i) dHH[i] = MFMA(w1h_[i][kt], bh, dHH[i]);
      }
      // wait for local L0's LDS stage of h0[t] (our x-input)
      const int sl3 = t % 3;
      while (__hip_atomic_load(&ctl[4 + sl3], __ATOMIC_ACQUIRE,
                               __HIP_MEMORY_SCOPE_WORKGROUP) < t) {}
      const char* sh = smem + L_H0 + sl3 * 16384;
      f4v eHH[2] = {z, z};
#pragma unroll
      for (int kt = 0; kt < 16; ++kt) {
        s8v bh = *(const s8v*)(sh + kt * 1024 + q * 256 + n * 16);
#pragma unroll
        for (int i = 0; i < 2; ++i) eHH[i] = MFMA(w1x_[i][kt], bh, eHH[i]);
      }
      // h0[t] consumed -> release back-pressure (per-wave, release orders LDS reads)
      if (lane == 0)
        __hip_atomic_store(&ctl[7 + (wave & 1)], t, __ATOMIC_RELEASE,
                           __HIP_MEMORY_SCOPE_WORKGROUP);
      // elementwise: 4 gates thread-local; publish via LDS transpose, dual store
      const u32 otag = ((u32)(u16)t) << 16;
      float hout[2];
#pragma unroll
      for (int ii = 0; ii < 2; ++ii) {
        f4v e = dHH[ii] + eHH[ii];
        float pi = e[0] + bias[ii][0], pf = e[1] + bias[ii][1];
        float pg = e[2] + bias[ii][2], po = e[3] + bias[ii][3];
        float ig = sigm(pi), fg = sigm(pf), gv = tanh_f(pg), og = sigm(po);
        c1[ii] = fg * c1[ii] + ig * gv;
        hout[ii] = og * tanh_f(c1[ii]);
        stg[n * 8 + ii * 4 + q] = otag | (u32)f2bf(hout[ii]);
      }
      asm volatile("s_waitcnt lgkmcnt(0)" ::: "memory");
      __builtin_amdgcn_sched_barrier(0);
      if (lane < 32) {
        u32x4 pv = *(const u32x4*)((const char*)stg + lane * 16);
        u32* dp = ringB + RIX32(t & 3, gr) + pub * 2 + lane * 4;
        asm volatile("global_store_dwordx4 %0, %1, off sc0\n\t"
                     "global_store_dwordx4 %0, %1, off sc1"
                     :: "v"(dp), "v"(pv) : "memory");
      }
      if (t == NT) {
#pragma unroll
        for (int ii = 0; ii < 2; ++ii)
          AT_ST((u32*)&fb32[(size_t)(gr * BG + n) * HDIM + jown[ii]],
                __float_as_uint(hout[ii]));
      }
    }
  }
}

// ---------------- final linear: out = h1[NT] @ lin_w^T + lin_b (fp32 h) ------
__global__ void final_linear(const float* __restrict__ fb32,
                             const float* __restrict__ lin_w,
                             const float* __restrict__ lin_b,
                             float* __restrict__ out) {
  int b = blockIdx.x, o = threadIdx.x;
  if (o < OUTDIM) {
    float acc = lin_b[o];
    const u32* hr = (const u32*)(fb32 + (size_t)b * HDIM);
    for (int j = 0; j < HDIM; ++j) {
      float h = __uint_as_float(AT_LD(hr + j));  // sc1: bypass any stale L2 line
      acc += h * lin_w[(size_t)o * HDIM + j];
    }
    out[b * OUTDIM + o] = acc;
  }
}

__global__ void sentinel_kernel(float* __restrict__ out, int nv) {
  int i = blockIdx.x * TPB + threadIdx.x;
  if (i < nv) out[i] = 1e30f;
}

extern "C" void kernel_launch(void* const* d_in, const int* in_sizes, int n_in,
                              void* d_out, int out_size, void* d_ws, size_t ws_size,
                              hipStream_t stream) {
  (void)in_sizes; (void)n_in;
  const float* x     = (const float*)d_in[0];
  const float* wih0  = (const float*)d_in[1];
  const float* whh0  = (const float*)d_in[2];
  const float* bih0  = (const float*)d_in[3];
  const float* bhh0  = (const float*)d_in[4];
  const float* wih1  = (const float*)d_in[5];
  const float* whh1  = (const float*)d_in[6];
  const float* bih1  = (const float*)d_in[7];
  const float* bhh1  = (const float*)d_in[8];
  const float* lin_w = (const float*)d_in[9];
  const float* lin_b = (const float*)d_in[10];
  float* out = (float*)d_out;
  char* ws = (char*)d_ws;

  if (ws_size < WS_NEEDED) {
    sentinel_kernel<<<(out_size + TPB - 1) / TPB, TPB, 0, stream>>>(out, out_size);
    return;
  }

  u32* ringA  = (u32*)(ws + RA_OFF);
  u32* ringB  = (u32*)(ws + RB_OFF);
  float* fb32 = (float*)(ws + FB32_OFF);

  lstm_fused<<<256, TPB, 0, stream>>>(x, wih0, whh0, bih0, bhh0,
                                      wih1, whh1, bih1, bhh1,
                                      ringA, ringB, fb32);
  final_linear<<<BTOT, 64, 0, stream>>>(fb32, lin_w, lin_b, out);
}

// Round 9
// 5180.788 us; speedup vs baseline: 1.7083x; 1.7083x over previous
//
#include <hip/hip_runtime.h>
#include <cstddef>
#include <cstdint>

typedef unsigned long long ull;
typedef unsigned short u16;
typedef unsigned int u32;
typedef __attribute__((ext_vector_type(8))) short s8v;   // 8 x bf16 (MFMA A/B frag)
typedef __attribute__((ext_vector_type(4))) float f4v;   // MFMA C/D frag
typedef __attribute__((ext_vector_type(4))) u32 u32x4;   // dwordx4 payload

#define GROUPS 8
#define BG     16
#define JS     16
#define TPB    256
#define NT     1024
#define HDIM   512
#define INDIM  17
#define OUTDIM 17
#define BTOT   128

// Cross-WG traffic: tag-in-data planes via relaxed agent atomics / sc1 vector
// ops (MALL). R2+R8 falsified every sc0/L2 fast path: cross-WG comm on this
// chip is MALL-only. NO release fences in the hot loop (R6: agent release
// emits buffer_wbl2 = catastrophic). Tag16|bf16 in each u32 self-validates
// under any load width -> wide non-atomic sc1 ops are safe.
#define AT_LD(p)   __hip_atomic_load((p), __ATOMIC_RELAXED, __HIP_MEMORY_SCOPE_AGENT)
#define AT_ST(p,v) __hip_atomic_store((p), (v), __ATOMIC_RELAXED, __HIP_MEMORY_SCOPE_AGENT)

// frag-order plane, u32 elements: entry = (step_tag << 16) | bf16_h.
// u32 idx(k,b) = (k>>5)*512 + ((k>>3)&3)*128 + b*8 + (k&7); plane = 8192 u32 = 32KB.
#define PLANE32 8192
#define WIDX(k, b) ((((k) >> 5) * 512) + ((((k) >> 3) & 3) * 128) + ((b) * 8) + ((k) & 7))

// ---------------- workspace ----------------
#define RA_OFF     ((size_t)0)
#define RING_BYTES ((size_t)4 * GROUPS * PLANE32 * 4)   // 4-slot ring, 1 MB
#define RB_OFF     (RA_OFF + RING_BYTES)
#define FB32_OFF   (RB_OFF + RING_BYTES)                // fp32 h1[NT]: 256 KB
#define WS_NEEDED  (FB32_OFF + (size_t)BTOT * HDIM * 4)
#define RIX32(sl, gr) (((size_t)(sl) * GROUPS + (gr)) * PLANE32)

// ---------------- LDS layout ----------------
#define L_H0   0                        // h0 stage ring: 3 slots x 16 KB (bf16 frag-order)
#define L_H1   49152                    // h1 stage: 16 KB
#define L_STG  65536                    // per-wave publish transpose: 4 x 512 B
#define L_CTL  67584                    // control ints (64 B)
#define LDS_SZ 82944                    // >80KB: 2 WGs cannot share a CU
// ctl: 0=ctrA 1=ctrB 4..6=stage_ready[3] 7,8=L1 per-wave progress (back-pressure)

__device__ __forceinline__ u16 f2bf(float f) {
  unsigned int u = __float_as_uint(f);
  u += 0x7FFFu + ((u >> 16) & 1u);
  return (u16)(u >> 16);
}
__device__ __forceinline__ float bf2f(u16 h) {
  return __uint_as_float(((unsigned int)h) << 16);
}
__device__ __forceinline__ float sigm(float x) { return 1.f / (1.f + __expf(-x)); }
__device__ __forceinline__ float tanh_f(float x) { return 2.f / (1.f + __expf(-2.f * x)) - 1.f; }

#define MFMA(a, b, c) __builtin_amdgcn_mfma_f32_16x16x32_bf16((a), (b), (c), 0, 0, 0)

// 16 x dwordx4 sc1 loads (MALL-served): one half-plane (16KB) per wave,
// 64 u32/lane. THE POLL: each iteration is the full read; tags verify freshness
// and the detecting iteration already holds the payload (no second RT).
__device__ __forceinline__ void sc1_read16(const char* base, u32x4 r[16]) {
  asm volatile(
      "global_load_dwordx4 %0, %16, off sc1\n\t"
      "global_load_dwordx4 %1, %16, off offset:1024 sc1\n\t"
      "global_load_dwordx4 %2, %16, off offset:2048 sc1\n\t"
      "global_load_dwordx4 %3, %16, off offset:3072 sc1\n\t"
      "global_load_dwordx4 %4, %17, off sc1\n\t"
      "global_load_dwordx4 %5, %17, off offset:1024 sc1\n\t"
      "global_load_dwordx4 %6, %17, off offset:2048 sc1\n\t"
      "global_load_dwordx4 %7, %17, off offset:3072 sc1\n\t"
      "global_load_dwordx4 %8, %18, off sc1\n\t"
      "global_load_dwordx4 %9, %18, off offset:1024 sc1\n\t"
      "global_load_dwordx4 %10, %18, off offset:2048 sc1\n\t"
      "global_load_dwordx4 %11, %18, off offset:3072 sc1\n\t"
      "global_load_dwordx4 %12, %19, off sc1\n\t"
      "global_load_dwordx4 %13, %19, off offset:1024 sc1\n\t"
      "global_load_dwordx4 %14, %19, off offset:2048 sc1\n\t"
      "global_load_dwordx4 %15, %19, off offset:3072 sc1\n\t"
      "s_waitcnt vmcnt(0)"
      : "=&v"(r[0]), "=&v"(r[1]), "=&v"(r[2]), "=&v"(r[3]),
        "=&v"(r[4]), "=&v"(r[5]), "=&v"(r[6]), "=&v"(r[7]),
        "=&v"(r[8]), "=&v"(r[9]), "=&v"(r[10]), "=&v"(r[11]),
        "=&v"(r[12]), "=&v"(r[13]), "=&v"(r[14]), "=&v"(r[15])
      : "v"(base), "v"(base + 4096), "v"(base + 8192), "v"(base + 12288)
      : "memory");
}

// 2-wave pair barrier via LDS monotonic counter (lane0 adds, all spin)
__device__ __forceinline__ void pbar(int* c, int& nbar, int lane) {
  ++nbar;
  if (lane == 0)
    (void)__hip_atomic_fetch_add(c, 1, __ATOMIC_RELEASE, __HIP_MEMORY_SCOPE_WORKGROUP);
  while (__hip_atomic_load(c, __ATOMIC_ACQUIRE, __HIP_MEMORY_SCOPE_WORKGROUP) < 2 * nbar) {}
}

// ---------------- fused 2-layer persistent LSTM, tag-in-data sync ---------------
// 256 WGs (1/CU). gr = bid&7 owns batches [gr*16,..); wg = bid>>3 owns j-slice.
// Waves 0-1 = L0; waves 2-3 = L1. OPERAND-SWAPPED MFMA: C = W(A) x h(B), A rows
// packed (j_local*4+gate) -> all 4 gates thread-local, no gate exchange.
// h comm = (tag<<16|bf16) u32. CONSUME: full-wide-read-as-poll (single RT on
// the chain: detect == read). Back-pressure hoisted to an LDS-only pre-spin.
// PUBLISH: per-wave LDS transpose -> 32 lanes x dwordx4 sc1 (contiguous 512B).
// Slot safety: WG at step s observed all peers' s-1 tags => all peers >= s-1 =>
// nobody still reads slot (s&3)'s old s-4 contents. Harness re-poisons ws
// (0xAAAA tag) so stale tags never match. Cell state fp32 in regs; h1 fp32 out.
__global__ __launch_bounds__(TPB, 1) void lstm_fused(
    const float* __restrict__ x,
    const float* __restrict__ wih0, const float* __restrict__ whh0,
    const float* __restrict__ bih0, const float* __restrict__ bhh0,
    const float* __restrict__ wih1, const float* __restrict__ whh1,
    const float* __restrict__ bih1, const float* __restrict__ bhh1,
    u32* __restrict__ ringA, u32* __restrict__ ringB,
    float* __restrict__ fb32)
{
  const int bid  = blockIdx.x;
  const int gr   = bid & 7;
  const int wg   = bid >> 3;
  const int j0   = wg * JS;
  const int tid  = threadIdx.x;
  const int wave = tid >> 6;
  const int lane = tid & 63;
  const int n    = lane & 15;        // own-index: B col (batch) / A row (j,g packed)
  const int q    = lane >> 4;        // k-sub-quad; also C-row quad -> own j_local
  const int k0   = q * 8;
  const int gidx = n & 3;            // gate for WEIGHT A-frag row
  const int jl   = n >> 2;           // j_local for WEIGHT A-frag row

  __shared__ __align__(16) char smem[LDS_SZ];
  int* ctl = (int*)(smem + L_CTL);
  u32* stg = (u32*)(smem + L_STG + (wave & 1) * 512 + (wave >> 1) * 1024);

  if (tid < 16) ctl[tid] = 0;

  // ---- init ring slot 0 = (tag=0, h=0) for own slice ----
  {
    int b_l = tid >> 4, j_l = tid & 15, jgw = j0 + j_l;
    int wo = WIDX(jgw, b_l);
    AT_ST(&ringA[RIX32(0, gr) + wo], 0u);
    AT_ST(&ringB[RIX32(0, gr) + wo], 0u);
  }
  __syncthreads();  // ctl visible; only __syncthreads in kernel

  const f4v z = {0.f, 0.f, 0.f, 0.f};
  const int half = wave & 1;              // which half-plane this wave polls+stages
  // wave's contiguous 64-ull publish block within the plane (ull units):
  const int pub = (wg >> 1) * 256 + ((wg & 1) * 2 + (wave & 1)) * 64;

  if (wave < 2) {
    // ================= L0 pipeline (waves 0,1) =================
    // chains ii=0,1 -> jc = wave*2+ii; this thread owns cells (b=n, j=j0+jc*4+q)
    int jown[2];
    float bias[2][4];
    s8v wxh[2], wxl[2];                 // wih0 A-frags (hi/lo), K=32 (17 padded)
    s8v whh_[2][16], whl_[2][16];       // whh0 A-frags (hi/lo)
#pragma unroll
    for (int i = 0; i < 2; ++i) {
      const int jc = wave * 2 + i;
      jown[i] = j0 + jc * 4 + q;
      const float* wr = wih0 + (size_t)(gidx * HDIM + j0 + jc * 4 + jl) * INDIM;
#pragma unroll
      for (int j = 0; j < 8; ++j) {
        int k = k0 + j;
        float v = (k < INDIM) ? wr[k] : 0.f;
        u16 hi = f2bf(v);
        wxh[i][j] = (short)hi;
        wxl[i][j] = (short)f2bf(v - bf2f(hi));
      }
      const float* hr = whh0 + (size_t)(gidx * HDIM + j0 + jc * 4 + jl) * HDIM;
#pragma unroll
      for (int kt = 0; kt < 16; ++kt)
#pragma unroll
        for (int j = 0; j < 8; ++j) {
          float v = hr[kt * 32 + k0 + j];
          u16 hi = f2bf(v);
          whh_[i][kt][j] = (short)hi;
          whl_[i][kt][j] = (short)f2bf(v - bf2f(hi));
        }
#pragma unroll
      for (int g = 0; g < 4; ++g)
        bias[i][g] = bih0[g * HDIM + jown[i]] + bhh0[g * HDIM + jown[i]];
    }
    float cc[2] = {0.f, 0.f};
    int nbar = 0;

    for (int s = 1; s <= NT + 1; ++s) {
      // x-part (no peer dependency): before the data-poll. B-frag = x (col=batch n)
      f4v xa[2] = {z, z};
      if (s <= NT) {
        const float* xr = x + ((size_t)(gr * BG + n) * NT + (s - 1)) * INDIM;
        s8v bxh, bxl;
#pragma unroll
        for (int j = 0; j < 8; ++j) {
          int k = k0 + j;
          float v = (k < INDIM) ? xr[k] : 0.f;
          u16 hi = f2bf(v);
          bxh[j] = (short)hi;
          bxl[j] = (short)f2bf(v - bf2f(hi));
        }
#pragma unroll
        for (int i = 0; i < 2; ++i) {
          xa[i] = MFMA(wxh[i], bxh, xa[i]);
          xa[i] = MFMA(wxh[i], bxl, xa[i]);
          xa[i] = MFMA(wxl[i], bxh, xa[i]);
        }
      }
      // back-pressure pre-spin (LDS-only, monotone): BOTH L1 waves must have
      // consumed h0[s-4] before we overwrite LDS slot (s-1)%3
      const int sl3 = (s - 1) % 3;
      for (;;) {
        int l1a = __hip_atomic_load(&ctl[7], __ATOMIC_ACQUIRE,
                                    __HIP_MEMORY_SCOPE_WORKGROUP);
        int l1b = __hip_atomic_load(&ctl[8], __ATOMIC_ACQUIRE,
                                    __HIP_MEMORY_SCOPE_WORKGROUP);
        if ((l1a < l1b ? l1a : l1b) >= s - 4) break;
        __builtin_amdgcn_s_sleep(1);
      }
      // full-wide-read-as-poll of h0[s-1] (slot (s-1)&3, tag s-1): the
      // detecting iteration already holds the payload -> single RT on chain
      {
        const char* srcb = (const char*)(ringA + RIX32((s - 1) & 3, gr))
                         + half * 16384;
        const u32 t32 = ((u32)(u16)(s - 1)) << 16;
        u32x4 r[16];
        const char* base = srcb + lane * 16;
        for (;;) {
          sc1_read16(base, r);
          u32 acc = 0;
#pragma unroll
          for (int i = 0; i < 16; ++i)
#pragma unroll
            for (int jj = 0; jj < 4; ++jj)
              acc |= (r[i][jj] ^ t32) & 0xFFFF0000u;
          if (__ballot(acc == 0) == ~0ULL) break;
          __builtin_amdgcn_s_sleep(1);
        }
        char* dst = smem + L_H0 + sl3 * 16384 + half * 8192;
#pragma unroll
        for (int i = 0; i < 16; ++i) {
          ull packed = (ull)((r[i][0] & 0xFFFFu) | (r[i][1] << 16))
                     | ((ull)((r[i][2] & 0xFFFFu) | (r[i][3] << 16)) << 32);
          *(ull*)(dst + (i * 64 + lane) * 8) = packed;
        }
      }
      pbar(&ctl[0], nbar, lane);                              // P1: stage visible
      if (wave == 0 && lane == 0)
        __hip_atomic_store(&ctl[4 + sl3], s - 1, __ATOMIC_RELEASE,
                           __HIP_MEMORY_SCOPE_WORKGROUP);
      if (s == NT + 1) break;  // tail step only feeds L1's last x-input

      // K-loop: 16 ds_read_b128 + 64 MFMA; A=Whh frags, B=h frags from LDS
      const char* sh = smem + L_H0 + sl3 * 16384;
      f4v cHH[2] = {z, z}, cHL[2] = {z, z};
#pragma unroll
      for (int kt = 0; kt < 16; ++kt) {
        s8v bh = *(const s8v*)(sh + kt * 1024 + q * 256 + n * 16);
#pragma unroll
        for (int i = 0; i < 2; ++i) {
          cHH[i] = MFMA(whh_[i][kt], bh, cHH[i]);
          cHL[i] = MFMA(whl_[i][kt], bh, cHL[i]);
        }
      }
      // elementwise: all 4 gates thread-local (C rows q*4+r). Publish via
      // intra-wave LDS transpose -> 32 lanes x dwordx4 sc1 (no barrier).
      const u32 otag = ((u32)(u16)s) << 16;
#pragma unroll
      for (int ii = 0; ii < 2; ++ii) {
        f4v e = xa[ii] + cHH[ii] + cHL[ii];
        float pi = e[0] + bias[ii][0], pf = e[1] + bias[ii][1];
        float pg = e[2] + bias[ii][2], po = e[3] + bias[ii][3];
        float ig = sigm(pi), fg = sigm(pf), gv = tanh_f(pg), og = sigm(po);
        cc[ii] = fg * cc[ii] + ig * gv;
        stg[n * 8 + ii * 4 + q] = otag | (u32)f2bf(og * tanh_f(cc[ii]));
      }
      asm volatile("s_waitcnt lgkmcnt(0)" ::: "memory");
      __builtin_amdgcn_sched_barrier(0);
      if (lane < 32) {
        u32x4 pv = *(const u32x4*)((const char*)stg + lane * 16);
        u32* dp = ringA + RIX32(s & 3, gr) + pub * 2 + lane * 4;
        asm volatile("global_store_dwordx4 %0, %1, off sc1"
                     :: "v"(dp), "v"(pv) : "memory");
      }
    }
  } else {
    // ================= L1 pipeline (waves 2,3) =================
    int jown[2];
    float bias[2][4];
    s8v w1x_[2][16], w1h_[2][16];   // wih1 / whh1 A-frags (hi only)
#pragma unroll
    for (int i = 0; i < 2; ++i) {
      const int jc = (wave - 2) * 2 + i;
      jown[i] = j0 + jc * 4 + q;
      const float* p1 = wih1 + (size_t)(gidx * HDIM + j0 + jc * 4 + jl) * HDIM;
      const float* p2 = whh1 + (size_t)(gidx * HDIM + j0 + jc * 4 + jl) * HDIM;
#pragma unroll
      for (int kt = 0; kt < 16; ++kt)
#pragma unroll
        for (int j = 0; j < 8; ++j) {
          w1x_[i][kt][j] = (short)f2bf(p1[kt * 32 + k0 + j]);
          w1h_[i][kt][j] = (short)f2bf(p2[kt * 32 + k0 + j]);
        }
#pragma unroll
      for (int g = 0; g < 4; ++g)
        bias[i][g] = bih1[g * HDIM + jown[i]] + bhh1[g * HDIM + jown[i]];
    }
    float c1[2] = {0.f, 0.f};
    int nbar = 0;

    for (int t = 1; t <= NT; ++t) {
      // full-wide-read-as-poll of h1[t-1] (slot (t-1)&3, tag t-1)
      {
        const char* srcb = (const char*)(ringB + RIX32((t - 1) & 3, gr))
                         + half * 16384;
        const u32 t32 = ((u32)(u16)(t - 1)) << 16;
        u32x4 r[16];
        const char* base = srcb + lane * 16;
        for (;;) {
          sc1_read16(base, r);
          u32 acc = 0;
#pragma unroll
          for (int i = 0; i < 16; ++i)
#pragma unroll
            for (int jj = 0; jj < 4; ++jj)
              acc |= (r[i][jj] ^ t32) & 0xFFFF0000u;
          if (__ballot(acc == 0) == ~0ULL) break;
          __builtin_amdgcn_s_sleep(1);
        }
        char* dst = smem + L_H1 + half * 8192;
#pragma unroll
        for (int i = 0; i < 16; ++i) {
          ull packed = (ull)((r[i][0] & 0xFFFFu) | (r[i][1] << 16))
                     | ((ull)((r[i][2] & 0xFFFFu) | (r[i][3] << 16)) << 32);
          *(ull*)(dst + (i * 64 + lane) * 8) = packed;
        }
      }
      pbar(&ctl[1], nbar, lane);                              // Q1: h1 staged
      // K-loop B: h1 recurrence (A=whh1 frags)
      const char* th = smem + L_H1;
      f4v dHH[2] = {z, z};
#pragma unroll
      for (int kt = 0; kt < 16; ++kt) {
        s8v bh = *(const s8v*)(th + kt * 1024 + q * 256 + n * 16);
#pragma unroll
        for (int i = 0; i < 2; ++i) dHH[i] = MFMA(w1h_[i][kt], bh, dHH[i]);
      }
      // wait for local L0's LDS stage of h0[t] (our x-input)
      const int sl3 = t % 3;
      while (__hip_atomic_load(&ctl[4 + sl3], __ATOMIC_ACQUIRE,
                               __HIP_MEMORY_SCOPE_WORKGROUP) < t) {}
      const char* sh = smem + L_H0 + sl3 * 16384;
      f4v eHH[2] = {z, z};
#pragma unroll
      for (int kt = 0; kt < 16; ++kt) {
        s8v bh = *(const s8v*)(sh + kt * 1024 + q * 256 + n * 16);
#pragma unroll
        for (int i = 0; i < 2; ++i) eHH[i] = MFMA(w1x_[i][kt], bh, eHH[i]);
      }
      // h0[t] consumed -> release back-pressure (per-wave, release orders LDS reads)
      if (lane == 0)
        __hip_atomic_store(&ctl[7 + (wave & 1)], t, __ATOMIC_RELEASE,
                           __HIP_MEMORY_SCOPE_WORKGROUP);
      // elementwise: 4 gates thread-local; publish via LDS transpose (coalesced)
      const u32 otag = ((u32)(u16)t) << 16;
      float hout[2];
#pragma unroll
      for (int ii = 0; ii < 2; ++ii) {
        f4v e = dHH[ii] + eHH[ii];
        float pi = e[0] + bias[ii][0], pf = e[1] + bias[ii][1];
        float pg = e[2] + bias[ii][2], po = e[3] + bias[ii][3];
        float ig = sigm(pi), fg = sigm(pf), gv = tanh_f(pg), og = sigm(po);
        c1[ii] = fg * c1[ii] + ig * gv;
        hout[ii] = og * tanh_f(c1[ii]);
        stg[n * 8 + ii * 4 + q] = otag | (u32)f2bf(hout[ii]);
      }
      asm volatile("s_waitcnt lgkmcnt(0)" ::: "memory");
      __builtin_amdgcn_sched_barrier(0);
      if (lane < 32) {
        u32x4 pv = *(const u32x4*)((const char*)stg + lane * 16);
        u32* dp = ringB + RIX32(t & 3, gr) + pub * 2 + lane * 4;
        asm volatile("global_store_dwordx4 %0, %1, off sc1"
                     :: "v"(dp), "v"(pv) : "memory");
      }
      if (t == NT) {
#pragma unroll
        for (int ii = 0; ii < 2; ++ii)
          AT_ST((u32*)&fb32[(size_t)(gr * BG + n) * HDIM + jown[ii]],
                __float_as_uint(hout[ii]));
      }
    }
  }
}

// ---------------- final linear: out = h1[NT] @ lin_w^T + lin_b (fp32 h) ------
__global__ void final_linear(const float* __restrict__ fb32,
                             const float* __restrict__ lin_w,
                             const float* __restrict__ lin_b,
                             float* __restrict__ out) {
  int b = blockIdx.x, o = threadIdx.x;
  if (o < OUTDIM) {
    float acc = lin_b[o];
    const u32* hr = (const u32*)(fb32 + (size_t)b * HDIM);
    for (int j = 0; j < HDIM; ++j) {
      float h = __uint_as_float(AT_LD(hr + j));  // sc1: bypass any stale L2 line
      acc += h * lin_w[(size_t)o * HDIM + j];
    }
    out[b * OUTDIM + o] = acc;
  }
}

__global__ void sentinel_kernel(float* __restrict__ out, int nv) {
  int i = blockIdx.x * TPB + threadIdx.x;
  if (i < nv) out[i] = 1e30f;
}

extern "C" void kernel_launch(void* const* d_in, const int* in_sizes, int n_in,
                              void* d_out, int out_size, void* d_ws, size_t ws_size,
                              hipStream_t stream) {
  (void)in_sizes; (void)n_in;
  const float* x     = (const float*)d_in[0];
  const float* wih0  = (const float*)d_in[1];
  const float* whh0  = (const float*)d_in[2];
  const float* bih0  = (const float*)d_in[3];
  const float* bhh0  = (const float*)d_in[4];
  const float* wih1  = (const float*)d_in[5];
  const float* whh1  = (const float*)d_in[6];
  const float* bih1  = (const float*)d_in[7];
  const float* bhh1  = (const float*)d_in[8];
  const float* lin_w = (const float*)d_in[9];
  const float* lin_b = (const float*)d_in[10];
  float* out = (float*)d_out;
  char* ws = (char*)d_ws;

  if (ws_size < WS_NEEDED) {
    sentinel_kernel<<<(out_size + TPB - 1) / TPB, TPB, 0, stream>>>(out, out_size);
    return;
  }

  u32* ringA  = (u32*)(ws + RA_OFF);
  u32* ringB  = (u32*)(ws + RB_OFF);
  float* fb32 = (float*)(ws + FB32_OFF);

  lstm_fused<<<256, TPB, 0, stream>>>(x, wih0, whh0, bih0, bhh0,
                                      wih1, whh1, bih1, bhh1,
                                      ringA, ringB, fb32);
  final_linear<<<BTOT, 64, 0, stream>>>(fb32, lin_w, lin_b, out);
}

// Round 11
// 4668.520 us; speedup vs baseline: 1.8958x; 1.1097x over previous
//
#include <hip/hip_runtime.h>
#include <cstddef>
#include <cstdint>

typedef unsigned long long ull;
typedef unsigned short u16;
typedef unsigned int u32;
typedef __attribute__((ext_vector_type(8))) short s8v;   // 8 x bf16 (MFMA A/B frag)
typedef __attribute__((ext_vector_type(4))) float f4v;   // MFMA C/D frag

#define GROUPS 8
#define BG     16
#define JS     16
#define TPB    256
#define NT     1024
#define HDIM   512
#define INDIM  17
#define OUTDIM 17
#define BTOT   128

// Cross-WG traffic: relaxed agent-scope atomics (sc1 -> MALL). No fences, no
// flags. Session ladder (R0-R9) falsified: sc0/L2 paths (stale / writeback
// storms), agent-RELEASE in-loop (buffer_wbl2), wide-op substitution (null),
// full-read-as-poll (negative), 512-thr WGs (VGPR spill). This two-stage
// tag-in-data design is the measured optimum (4641 us).
#define AT_LD(p)   __hip_atomic_load((p), __ATOMIC_RELAXED, __HIP_MEMORY_SCOPE_AGENT)
#define AT_ST(p,v) __hip_atomic_store((p), (v), __ATOMIC_RELAXED, __HIP_MEMORY_SCOPE_AGENT)

// frag-order plane, u32 elements: entry = (step_tag << 16) | bf16_h.
// u32 idx(k,b) = (k>>5)*512 + ((k>>3)&3)*128 + b*8 + (k&7); plane = 8192 u32 = 32KB.
// Tag+value share one u32 -> one 8B atomic load can never tear them apart.
#define PLANE32 8192
#define WIDX(k, b) ((((k) >> 5) * 512) + ((((k) >> 3) & 3) * 128) + ((b) * 8) + ((k) & 7))
#define SLICE(wg)  (((wg) >> 1) * 512 + ((wg) & 1) * 256)   // WG's contiguous 256-u32 slice

// ---------------- workspace ----------------
#define RA_OFF     ((size_t)0)
#define RING_BYTES ((size_t)4 * GROUPS * PLANE32 * 4)   // 4-slot ring, 1 MB
#define RB_OFF     (RA_OFF + RING_BYTES)
#define FB32_OFF   (RB_OFF + RING_BYTES)                // fp32 h1[NT]: 256 KB
#define WS_NEEDED  (FB32_OFF + (size_t)BTOT * HDIM * 4)
#define RIX32(sl, gr) (((size_t)(sl) * GROUPS + (gr)) * PLANE32)

// ---------------- LDS layout ----------------
#define L_H0   0                        // h0 stage ring: 3 slots x 16 KB (u16 frag-order)
#define L_H1   49152                    // h1 stage: 16 KB
#define L_EXA  65536                    // gate exchange L0, 4 KB
#define L_EXB  69632                    // gate exchange L1, 4 KB
#define L_HOA  73728                    // h out staging L0: 256 u32 = 1 KB
#define L_HOB  74752                    // h out staging L1: 1 KB
#define L_CTL  75776                    // control ints (64 B)
#define LDS_SZ 81920                    // padded >80KB: forces 1 WG/CU
// ctl: 0=ctrA 1=ctrB 4..6=stage_ready[3] 7=L1 progress (back-pressure)

__device__ __forceinline__ u16 f2bf(float f) {
  unsigned int u = __float_as_uint(f);
  u += 0x7FFFu + ((u >> 16) & 1u);
  return (u16)(u >> 16);
}
__device__ __forceinline__ float bf2f(u16 h) {
  return __uint_as_float(((unsigned int)h) << 16);
}
__device__ __forceinline__ float sigm(float x) { return 1.f / (1.f + __expf(-x)); }
__device__ __forceinline__ float tanh_f(float x) { return 2.f / (1.f + __expf(-2.f * x)) - 1.f; }

#define MFMA(a, b, c) __builtin_amdgcn_mfma_f32_16x16x32_bf16((a), (b), (c), 0, 0, 0)

// 2-wave pair barrier via LDS monotonic counter (lane0 adds, all spin)
__device__ __forceinline__ void pbar(int* c, int& nbar, int lane) {
  ++nbar;
  if (lane == 0)
    (void)__hip_atomic_fetch_add(c, 1, __ATOMIC_RELEASE, __HIP_MEMORY_SCOPE_WORKGROUP);
  while (__hip_atomic_load(c, __ATOMIC_ACQUIRE, __HIP_MEMORY_SCOPE_WORKGROUP) < 2 * nbar) {}
}

// ---------------- fused 2-layer persistent LSTM, tag-in-data sync ---------------
// 256 WGs (1/CU). gr = bid&7 owns batches [gr*16,..); wg = bid>>3 owns j-slice.
// Waves 0-1 = L0 pipeline; waves 2-3 = L1. h comm = (tag<<16|bf16) u32 via MALL;
// consumers poll the data itself (no flags, no drains). Two-stage poll: cheap
// 1-u64/lane subset spin (samples all 16 peer slices in this half, incl. the
// late ho1 store block), then ONE full read + tag-verify (tag-in-data => safe).
// Publish is direct per-thread u32 stores (no LDS bounce, no 3rd pair barrier).
// Slot safety: WG at step s observed all peers' s-1 tags => all peers >= s-1 =>
// nobody still reads slot (s&3)'s old s-4 contents. Harness re-poisons ws
// (0xAAAA tag) so stale tags never match. Cell state fp32 in regs; h1 fp32 out.
//
// CEILING NOTE (session R0-R9): bound by 1024 serial 32-WG all-to-alls, each
// ~4.5us (MALL store-visibility + probe + max-of-peers jitter). Not HBM-bound
// (2.3%) nor MFMA-bound (9%). Weight distribution forces the all-to-all
// (2MB/CU replication impossible - R5 spill proof).
__global__ __launch_bounds__(TPB, 1) void lstm_fused(
    const float* __restrict__ x,
    const float* __restrict__ wih0, const float* __restrict__ whh0,
    const float* __restrict__ bih0, const float* __restrict__ bhh0,
    const float* __restrict__ wih1, const float* __restrict__ whh1,
    const float* __restrict__ bih1, const float* __restrict__ bhh1,
    u32* __restrict__ ringA, u32* __restrict__ ringB,
    float* __restrict__ fb32)
{
  const int bid  = blockIdx.x;
  const int gr   = bid & 7;
  const int wg   = bid >> 3;
  const int j0   = wg * JS;
  const int tid  = threadIdx.x;
  const int wave = tid >> 6;
  const int lane = tid & 63;
  const int n    = lane & 15;        // A-frag row (batch) / B-frag col (j)
  const int q    = lane >> 4;        // k-sub-quad
  const int k0   = q * 8;

  __shared__ __align__(16) char smem[LDS_SZ];
  int* ctl = (int*)(smem + L_CTL);
  float* exgA = (float*)(smem + L_EXA);
  float* exgB = (float*)(smem + L_EXB);

  if (tid < 8) ctl[tid] = 0;

  // ---- init ring slot 0 = (tag=0, h=0) for own slice ----
  {
    int b_l = tid >> 4, j_l = tid & 15, jg = j0 + j_l;
    int wo = WIDX(jg, b_l);
    AT_ST(&ringA[RIX32(0, gr) + wo], 0u);
    AT_ST(&ringB[RIX32(0, gr) + wo], 0u);
  }
  __syncthreads();  // ctl visible; only __syncthreads in kernel

  const f4v z = {0.f, 0.f, 0.f, 0.f};
  const int p  = (wave & 1) * 64 + lane;  // pair-tid 0..127
  const int jq = p & 15, b0 = p >> 4;     // cells (b0,jq) and (b0+8,jq)
  const int jg = j0 + jq;
  const int ho0 = (jq >> 3) * 128 + b0 * 8 + (jq & 7);        // hout u32 idx
  const int ho1 = (jq >> 3) * 128 + (b0 + 8) * 8 + (jq & 7);
  const int slice = SLICE(wg);
  const int half = wave & 1;              // which half-plane this wave stages
  // subset sample: lane covers peer slice (lane>>2) of this half, word (lane&3)*32
  const int sub = (lane >> 2) * 128 + (lane & 3) * 32;
  const ull TMASK = 0xFFFF0000FFFF0000ULL;

  if (wave < 2) {
    // ================= L0 pipeline (waves 0,1) =================
    const int g0 = wave * 2;  // gates g0, g0+1 (full K)
    s8v wx_h[2], wx_l[2];
#pragma unroll
    for (int i = 0; i < 2; ++i) {
      const float* wr = wih0 + (size_t)((g0 + i) * HDIM + j0 + n) * INDIM;
#pragma unroll
      for (int j = 0; j < 8; ++j) {
        int k = k0 + j;
        float v = (k < INDIM) ? wr[k] : 0.f;
        u16 hi = f2bf(v);
        wx_h[i][j] = (short)hi;
        wx_l[i][j] = (short)f2bf(v - bf2f(hi));
      }
    }
    s8v wh_h[2][16], wh_l[2][16];
#pragma unroll
    for (int i = 0; i < 2; ++i) {
      const float* wr = whh0 + (size_t)((g0 + i) * HDIM + j0 + n) * HDIM;
#pragma unroll
      for (int kt = 0; kt < 16; ++kt)
#pragma unroll
        for (int j = 0; j < 8; ++j) {
          float v = wr[kt * 32 + k0 + j];
          u16 hi = f2bf(v);
          wh_h[i][kt][j] = (short)hi;
          wh_l[i][kt][j] = (short)f2bf(v - bf2f(hi));
        }
    }
    float bias[4];
#pragma unroll
    for (int g = 0; g < 4; ++g) bias[g] = bih0[g * HDIM + jg] + bhh0[g * HDIM + jg];
    float c0a = 0.f, c0b = 0.f;
    int nbar = 0;

    for (int s = 1; s <= NT + 1; ++s) {
      // x-part (no peer dependency): before the data-poll
      f4v xa[2] = {z, z};
      if (s <= NT) {
        const float* xr = x + ((size_t)(gr * BG + n) * NT + (s - 1)) * INDIM;
        s8v axh, axl;
#pragma unroll
        for (int j = 0; j < 8; ++j) {
          int k = k0 + j;
          float v = (k < INDIM) ? xr[k] : 0.f;
          u16 hi = f2bf(v);
          axh[j] = (short)hi;
          axl[j] = (short)f2bf(v - bf2f(hi));
        }
#pragma unroll
        for (int i = 0; i < 2; ++i) {
          xa[i] = MFMA(axh, wx_h[i], xa[i]);
          xa[i] = MFMA(axl, wx_h[i], xa[i]);
          xa[i] = MFMA(axh, wx_l[i], xa[i]);
        }
      }
      // two-stage tag-poll + stage own half of h0[s-1] (slot (s-1)&3, tag s-1);
      // back-pressure: L1 must have finished step s-4 before LDS slot reuse
      const int sl3 = (s - 1) % 3;
      {
        const ull* src = (const ull*)(ringA + RIX32((s - 1) & 3, gr)) + half * 2048;
        const ull tg = (ull)(u16)(s - 1);
        const ull pat = (tg << 16) | (tg << 48);
        // stage 1: cheap subset spin (512B/wave/iter instead of 16KB)
        for (;;) {
          ull w = AT_LD(src + sub);
          int l1t = __hip_atomic_load(&ctl[7], __ATOMIC_ACQUIRE,
                                      __HIP_MEMORY_SCOPE_WORKGROUP);
          if (__ballot((((w ^ pat) & TMASK) == 0) & (l1t >= s - 4)) == ~0ULL) break;
          __builtin_amdgcn_s_sleep(1);
        }
        // stage 2: one full read + verify (retry rare; tags validate every word)
        ull v[32];
        for (;;) {
          ull acc = 0;
#pragma unroll
          for (int i = 0; i < 16; ++i) {
            v[2 * i]     = AT_LD(src + (i * 64 + lane) * 2);
            v[2 * i + 1] = AT_LD(src + (i * 64 + lane) * 2 + 1);
          }
#pragma unroll
          for (int i = 0; i < 32; ++i) acc |= (v[i] ^ pat) & TMASK;
          if (__ballot(acc == 0) == ~0ULL) break;
          __builtin_amdgcn_s_sleep(1);
        }
        char* dst = smem + L_H0 + sl3 * 16384 + half * 8192;
#pragma unroll
        for (int i = 0; i < 16; ++i) {
          ull a = v[2 * i], b = v[2 * i + 1];
          ull packed = (a & 0xFFFFULL) | ((a >> 16) & 0xFFFF0000ULL)
                     | ((b & 0xFFFFULL) << 32) | (((b >> 16) & 0xFFFF0000ULL) << 32);
          *(ull*)(dst + (i * 64 + lane) * 8) = packed;
        }
      }
      pbar(&ctl[0], nbar, lane);                              // P1: stage visible
      if (wave == 0 && lane == 0)
        __hip_atomic_store(&ctl[4 + sl3], s - 1, __ATOMIC_RELEASE,
                           __HIP_MEMORY_SCOPE_WORKGROUP);
      if (s == NT + 1) break;  // tail step only feeds L1's last x-input

      // K-loop: 16 ds_read_b128 + 64 MFMA (2 gates x 16kt x {Wh,Wl})
      const char* sh = smem + L_H0 + sl3 * 16384;
      f4v cHH[2] = {z, z}, cHL[2] = {z, z};
#pragma unroll
      for (int kt = 0; kt < 16; ++kt) {
        s8v ah = *(const s8v*)(sh + kt * 1024 + q * 256 + n * 16);
#pragma unroll
        for (int i = 0; i < 2; ++i) {
          cHH[i] = MFMA(ah, wh_h[i][kt], cHH[i]);
          cHL[i] = MFMA(ah, wh_l[i][kt], cHL[i]);
        }
      }
#pragma unroll
      for (int i = 0; i < 2; ++i) {
        f4v e = xa[i] + cHH[i] + cHL[i];
#pragma unroll
        for (int r = 0; r < 4; ++r)
          exgA[(g0 + i) * 256 + (q * 4 + r) * 16 + n] = e[r];
      }
      pbar(&ctl[0], nbar, lane);                              // P2: preacts ready
      // elementwise: 2 cells/thread -> (tag|h) published DIRECTLY to ring
      const u32 otag = ((u32)(u16)s) << 16;
      u32* d = (u32*)(ringA + RIX32(s & 3, gr) + slice);
      {
        float pi = exgA[0 * 256 + b0 * 16 + jq] + bias[0];
        float pf = exgA[1 * 256 + b0 * 16 + jq] + bias[1];
        float pg = exgA[2 * 256 + b0 * 16 + jq] + bias[2];
        float po = exgA[3 * 256 + b0 * 16 + jq] + bias[3];
        float ig = sigm(pi), fg = sigm(pf), gg = tanh_f(pg), og = sigm(po);
        c0a = fg * c0a + ig * gg;
        AT_ST(d + ho0, otag | (u32)f2bf(og * tanh_f(c0a)));
      }
      {
        float pi = exgA[0 * 256 + (b0 + 8) * 16 + jq] + bias[0];
        float pf = exgA[1 * 256 + (b0 + 8) * 16 + jq] + bias[1];
        float pg = exgA[2 * 256 + (b0 + 8) * 16 + jq] + bias[2];
        float po = exgA[3 * 256 + (b0 + 8) * 16 + jq] + bias[3];
        float ig = sigm(pi), fg = sigm(pf), gg = tanh_f(pg), og = sigm(po);
        c0b = fg * c0b + ig * gg;
        AT_ST(d + ho1, otag | (u32)f2bf(og * tanh_f(c0b)));
      }
    }
  } else {
    // ================= L1 pipeline (waves 2,3) =================
    const int g0 = (wave - 2) * 2;  // gates g0, g0+1; wih1/whh1 hi-only
    s8v w1x[2][16], w1h[2][16];
#pragma unroll
    for (int i = 0; i < 2; ++i) {
      const float* p1 = wih1 + (size_t)((g0 + i) * HDIM + j0 + n) * HDIM;
      const float* p2 = whh1 + (size_t)((g0 + i) * HDIM + j0 + n) * HDIM;
#pragma unroll
      for (int kt = 0; kt < 16; ++kt)
#pragma unroll
        for (int j = 0; j < 8; ++j) {
          w1x[i][kt][j] = (short)f2bf(p1[kt * 32 + k0 + j]);
          w1h[i][kt][j] = (short)f2bf(p2[kt * 32 + k0 + j]);
        }
    }
    float bias[4];
#pragma unroll
    for (int g = 0; g < 4; ++g) bias[g] = bih1[g * HDIM + jg] + bhh1[g * HDIM + jg];
    float c1a = 0.f, c1b = 0.f;
    int nbar = 0;

    for (int t = 1; t <= NT; ++t) {
      // two-stage tag-poll + stage own half of h1[t-1] (slot (t-1)&3, tag t-1)
      {
        const ull* src = (const ull*)(ringB + RIX32((t - 1) & 3, gr)) + half * 2048;
        const ull tg = (ull)(u16)(t - 1);
        const ull pat = (tg << 16) | (tg << 48);
        for (;;) {
          ull w = AT_LD(src + sub);
          if (__ballot(((w ^ pat) & TMASK) == 0) == ~0ULL) break;
          __builtin_amdgcn_s_sleep(1);
        }
        ull v[32];
        for (;;) {
          ull acc = 0;
#pragma unroll
          for (int i = 0; i < 16; ++i) {
            v[2 * i]     = AT_LD(src + (i * 64 + lane) * 2);
            v[2 * i + 1] = AT_LD(src + (i * 64 + lane) * 2 + 1);
          }
#pragma unroll
          for (int i = 0; i < 32; ++i) acc |= (v[i] ^ pat) & TMASK;
          if (__ballot(acc == 0) == ~0ULL) break;
          __builtin_amdgcn_s_sleep(1);
        }
        char* dst = smem + L_H1 + half * 8192;
#pragma unroll
        for (int i = 0; i < 16; ++i) {
          ull a = v[2 * i], b = v[2 * i + 1];
          ull packed = (a & 0xFFFFULL) | ((a >> 16) & 0xFFFF0000ULL)
                     | ((b & 0xFFFFULL) << 32) | (((b >> 16) & 0xFFFF0000ULL) << 32);
          *(ull*)(dst + (i * 64 + lane) * 8) = packed;
        }
      }
      pbar(&ctl[1], nbar, lane);                              // Q1: h1 staged
      // K-loop B: h1 recurrence
      const char* th = smem + L_H1;
      f4v dHH[2] = {z, z};
#pragma unroll
      for (int kt = 0; kt < 16; ++kt) {
        s8v ah = *(const s8v*)(th + kt * 1024 + q * 256 + n * 16);
#pragma unroll
        for (int i = 0; i < 2; ++i) dHH[i] = MFMA(ah, w1h[i][kt], dHH[i]);
      }
      // wait for local L0's LDS stage of h0[t] (our x-input)
      const int sl3 = t % 3;
      while (__hip_atomic_load(&ctl[4 + sl3], __ATOMIC_ACQUIRE,
                               __HIP_MEMORY_SCOPE_WORKGROUP) < t) {}
      const char* sh = smem + L_H0 + sl3 * 16384;
      f4v eHH[2] = {z, z};
#pragma unroll
      for (int kt = 0; kt < 16; ++kt) {
        s8v ah = *(const s8v*)(sh + kt * 1024 + q * 256 + n * 16);
#pragma unroll
        for (int i = 0; i < 2; ++i) eHH[i] = MFMA(ah, w1x[i][kt], eHH[i]);
      }
#pragma unroll
      for (int i = 0; i < 2; ++i) {
        f4v e = dHH[i] + eHH[i];
#pragma unroll
        for (int r = 0; r < 4; ++r)
          exgB[(g0 + i) * 256 + (q * 4 + r) * 16 + n] = e[r];
      }
      pbar(&ctl[1], nbar, lane);                              // Q2: preacts ready
      const u32 otag = ((u32)(u16)t) << 16;
      u32* d = (u32*)(ringB + RIX32(t & 3, gr) + slice);
      {
        float pi = exgB[0 * 256 + b0 * 16 + jq] + bias[0];
        float pf = exgB[1 * 256 + b0 * 16 + jq] + bias[1];
        float pg = exgB[2 * 256 + b0 * 16 + jq] + bias[2];
        float po = exgB[3 * 256 + b0 * 16 + jq] + bias[3];
        float ig = sigm(pi), fg = sigm(pf), gg = tanh_f(pg), og = sigm(po);
        c1a = fg * c1a + ig * gg;
        float h = og * tanh_f(c1a);
        AT_ST(d + ho0, otag | (u32)f2bf(h));
        if (t == NT)
          AT_ST((u32*)&fb32[(size_t)(gr * BG + b0) * HDIM + jg], __float_as_uint(h));
      }
      {
        float pi = exgB[0 * 256 + (b0 + 8) * 16 + jq] + bias[0];
        float pf = exgB[1 * 256 + (b0 + 8) * 16 + jq] + bias[1];
        float pg = exgB[2 * 256 + (b0 + 8) * 16 + jq] + bias[2];
        float po = exgB[3 * 256 + (b0 + 8) * 16 + jq] + bias[3];
        float ig = sigm(pi), fg = sigm(pf), gg = tanh_f(pg), og = sigm(po);
        c1b = fg * c1b + ig * gg;
        float h = og * tanh_f(c1b);
        AT_ST(d + ho1, otag | (u32)f2bf(h));
        if (t == NT)
          AT_ST((u32*)&fb32[(size_t)(gr * BG + b0 + 8) * HDIM + jg], __float_as_uint(h));
      }
      if (wave == 2 && lane == 0)
        __hip_atomic_store(&ctl[7], t, __ATOMIC_RELEASE,
                           __HIP_MEMORY_SCOPE_WORKGROUP);  // local back-pressure
    }
  }
}

// ---------------- final linear: out = h1[NT] @ lin_w^T + lin_b (fp32 h) ------
__global__ void final_linear(const float* __restrict__ fb32,
                             const float* __restrict__ lin_w,
                             const float* __restrict__ lin_b,
                             float* __restrict__ out) {
  int b = blockIdx.x, o = threadIdx.x;
  if (o < OUTDIM) {
    float acc = lin_b[o];
    const u32* hr = (const u32*)(fb32 + (size_t)b * HDIM);
    for (int j = 0; j < HDIM; ++j) {
      float h = __uint_as_float(AT_LD(hr + j));  // sc1: bypass any stale L2 line
      acc += h * lin_w[(size_t)o * HDIM + j];
    }
    out[b * OUTDIM + o] = acc;
  }
}

__global__ void sentinel_kernel(float* __restrict__ out, int nv) {
  int i = blockIdx.x * TPB + threadIdx.x;
  if (i < nv) out[i] = 1e30f;
}

extern "C" void kernel_launch(void* const* d_in, const int* in_sizes, int n_in,
                              void* d_out, int out_size, void* d_ws, size_t ws_size,
                              hipStream_t stream) {
  (void)in_sizes; (void)n_in;
  const float* x     = (const float*)d_in[0];
  const float* wih0  = (const float*)d_in[1];
  const float* whh0  = (const float*)d_in[2];
  const float* bih0  = (const float*)d_in[3];
  const float* bhh0  = (const float*)d_in[4];
  const float* wih1  = (const float*)d_in[5];
  const float* whh1  = (const float*)d_in[6];
  const float* bih1  = (const float*)d_in[7];
  const float* bhh1  = (const float*)d_in[8];
  const float* lin_w = (const float*)d_in[9];
  const float* lin_b = (const float*)d_in[10];
  float* out = (float*)d_out;
  char* ws = (char*)d_ws;

  if (ws_size < WS_NEEDED) {
    sentinel_kernel<<<(out_size + TPB - 1) / TPB, TPB, 0, stream>>>(out, out_size);
    return;
  }

  u32* ringA  = (u32*)(ws + RA_OFF);
  u32* ringB  = (u32*)(ws + RB_OFF);
  float* fb32 = (float*)(ws + FB32_OFF);

  lstm_fused<<<256, TPB, 0, stream>>>(x, wih0, whh0, bih0, bhh0,
                                      wih1, whh1, bih1, bhh1,
                                      ringA, ringB, fb32);
  final_linear<<<BTOT, 64, 0, stream>>>(fb32, lin_w, lin_b, out);
}